// Round 1
// baseline (258.907 us; speedup 1.0000x reference)
//
#include <hip/hip_runtime.h>

// KGL: per-patch kernel generation.
//  x: (8, 768, 768, 9) fp32. PSZ=24 -> p1=p2=32, N=1024, N*B=8192 patches.
//  Patch flat index j = b*1024 + pi*32 + pj (raw-reshape preserves buffer order).
//  out[0 .. 663551]        = wg1: conv3x3 stride8 (pad=0 -> 3x3x9) clipped per-oc over spatial
//  out[663552 .. 1327103]  = wg2: (GAP @ dense_w + b) as 9x9, clipped per-column over rows

#define PSZ 24
#define NCH 9
#define HW 768
#define PATCH_ELEMS (PSZ*PSZ*NCH)   // 5184
#define NPIX (PSZ*PSZ)              // 576
#define ROWF (PSZ*NCH)              // 216 floats per patch row
#define OUT1_OFF 0
#define OUT2_OFF 663552

__global__ __launch_bounds__(256) void kgl_kernel(
    const float* __restrict__ x,
    const float* __restrict__ conv_w,   // (3,3,9,9) HWIO flat
    const float* __restrict__ conv_b,   // (9,)
    const float* __restrict__ dense_w,  // (9,81)
    const float* __restrict__ dense_b,  // (81,)
    float* __restrict__ out)
{
    __shared__ float patch[PATCH_ELEMS];
    __shared__ float cw[729];
    __shared__ float co_s[81];
    __shared__ float d_s[81];
    __shared__ float gap_s[NCH];
    __shared__ float sc1[NCH];
    __shared__ float sc2[NCH];
    __shared__ float red[4*NCH];

    const int j   = blockIdx.x;
    const int b   = j >> 10;
    const int rem = j & 1023;
    const int pi  = rem >> 5;
    const int pj  = rem & 31;
    const int tid = threadIdx.x;

    // ---- Phase A: stage conv_w and the patch into LDS ----
    for (int i = tid; i < 729; i += 256) cw[i] = conv_w[i];

    const size_t base = ((size_t)(b*HW + pi*PSZ) * HW + (size_t)pj*PSZ) * NCH;
    for (int e = tid; e < PATCH_ELEMS; e += 256) {
        int r = e / ROWF;
        int t = e - r*ROWF;
        patch[e] = x[base + (size_t)r*(HW*NCH) + t];
    }
    __syncthreads();

    // ---- Phase B: GAP partial sums (all threads) + conv (threads 0..80) ----
    float cs[NCH];
    #pragma unroll
    for (int c = 0; c < NCH; ++c) cs[c] = 0.f;
    for (int p = tid; p < NPIX; p += 256) {
        const float* pp = &patch[p*NCH];
        #pragma unroll
        for (int c = 0; c < NCH; ++c) cs[c] += pp[c];
    }
    const int lane = tid & 63;
    const int wave = tid >> 6;
    #pragma unroll
    for (int c = 0; c < NCH; ++c) {
        float v = cs[c];
        #pragma unroll
        for (int off = 32; off > 0; off >>= 1) v += __shfl_down(v, off, 64);
        if (lane == 0) red[wave*NCH + c] = v;
    }

    if (tid < 81) {
        const int oy = tid / 27;
        const int ox = (tid / 9) % 3;
        const int oc = tid % 9;
        float acc = conv_b[oc];
        #pragma unroll
        for (int ky = 0; ky < 3; ++ky) {
            #pragma unroll
            for (int kx = 0; kx < 3; ++kx) {
                const float* pp = &patch[(oy*8+ky)*ROWF + (ox*8+kx)*NCH];
                const float* ww = &cw[((ky*3+kx)*9)*9 + oc];
                #pragma unroll
                for (int ic = 0; ic < 9; ++ic) acc += pp[ic] * ww[ic*9];
            }
        }
        co_s[tid] = acc;
    }
    __syncthreads();

    // ---- Phase C: finalize GAP; wg1 clip scales ----
    if (tid < NCH) {
        float s = red[tid] + red[NCH+tid] + red[2*NCH+tid] + red[3*NCH+tid];
        gap_s[tid] = s * (1.0f / (float)NPIX);

        float n2 = 0.f;
        #pragma unroll
        for (int s9 = 0; s9 < 9; ++s9) {
            float v = co_s[s9*9 + tid];
            n2 += v*v;
        }
        sc1[tid] = 1.0f / fmaxf(sqrtf(n2), 1.0f);
    }
    __syncthreads();

    // ---- Phase D: dense (needs gap), write wg1 ----
    if (tid < 81) {
        float acc = dense_b[tid];
        #pragma unroll
        for (int c = 0; c < NCH; ++c) acc += gap_s[c] * dense_w[c*81 + tid];
        d_s[tid] = acc;

        out[OUT1_OFF + (size_t)j*81 + tid] = co_s[tid] * sc1[tid % 9];
    }
    __syncthreads();

    // ---- Phase E: wg2 clip scales (norm over rows a, per column b) ----
    if (tid < NCH) {
        float n2 = 0.f;
        #pragma unroll
        for (int a = 0; a < 9; ++a) {
            float v = d_s[a*9 + tid];
            n2 += v*v;
        }
        sc2[tid] = 1.0f / fmaxf(sqrtf(n2), 1.0f);
    }
    __syncthreads();

    // ---- Phase F: write wg2 ----
    if (tid < 81) {
        out[OUT2_OFF + (size_t)j*81 + tid] = d_s[tid] * sc2[tid % 9];
    }
}

extern "C" void kernel_launch(void* const* d_in, const int* in_sizes, int n_in,
                              void* d_out, int out_size, void* d_ws, size_t ws_size,
                              hipStream_t stream) {
    const float* x       = (const float*)d_in[0];
    const float* conv_w  = (const float*)d_in[1];
    const float* conv_b  = (const float*)d_in[2];
    const float* dense_w = (const float*)d_in[3];
    const float* dense_b = (const float*)d_in[4];
    float* out = (float*)d_out;

    // 8192 patches, one block each
    kgl_kernel<<<8192, 256, 0, stream>>>(x, conv_w, conv_b, dense_w, dense_b, out);
}

// Round 2
// 241.293 us; speedup vs baseline: 1.0730x; 1.0730x over previous
//
#include <hip/hip_runtime.h>

// KGL: per-patch kernel generation.
//  x: (8, 768, 768, 9) fp32. PSZ=24 -> p1=p2=32, N=1024, N*B=8192 patches.
//  Patch flat index j = b*1024 + pi*32 + pj (raw-reshape preserves buffer order).
//  out[0 .. 663551]        = wg1: conv3x3 stride8 (pad=0 -> 3x3) clipped per-oc over spatial
//  out[663552 .. 1327103]  = wg2: (GAP @ dense_w + b) as 9x9, clipped per-column over rows

#define PSZ 24
#define NCH 9
#define HW 768
#define PATCH_ELEMS (PSZ*PSZ*NCH)   // 5184 floats = 1296 float4
#define PATCH_V4 1296
#define NPIX (PSZ*PSZ)              // 576
#define ROWF (PSZ*NCH)              // 216 floats per patch row (= 54 float4, 16B-aligned)
#define ROWV4 54
#define XROWF (HW*NCH)              // 6912 floats per image row
#define OUT1_OFF 0
#define OUT2_OFF 663552

__device__ inline void async_load16(const void* g, void* l) {
    __builtin_amdgcn_global_load_lds(
        (const __attribute__((address_space(1))) void*)g,
        (__attribute__((address_space(3))) void*)l, 16, 0, 0);
}

__global__ __launch_bounds__(256) void kgl_kernel(
    const float* __restrict__ x,
    const float* __restrict__ conv_w,   // (3,3,9,9) HWIO flat, 729
    const float* __restrict__ conv_b,   // (9,)
    const float* __restrict__ dense_w,  // (9,81)
    const float* __restrict__ dense_b,  // (81,)
    float* __restrict__ out)
{
    __shared__ __align__(16) float patch[PATCH_ELEMS];
    __shared__ __align__(16) float cw[732];      // 729 used
    __shared__ __align__(16) float colsum[ROWF]; // 216 column sums
    __shared__ float co_s[81];
    __shared__ float d_s[81];
    __shared__ float gap_s[NCH];
    __shared__ float sc1[NCH];
    __shared__ float sc2[NCH];

    const int j   = blockIdx.x;
    const int b   = j >> 10;
    const int rem = j & 1023;
    const int pi  = rem >> 5;
    const int pj  = rem & 31;
    const int tid = threadIdx.x;

    // ---- Phase A: stage conv_w (float4) and patch (global_load_lds x16) ----
    if (tid < 182) {
        reinterpret_cast<float4*>(cw)[tid] =
            reinterpret_cast<const float4*>(conv_w)[tid];
    } else if (tid == 182) {
        cw[728] = conv_w[728];
    }

    const size_t base = ((size_t)(b*HW + pi*PSZ) * HW + (size_t)pj*PSZ) * NCH;
    const float* gbase = x + base;
    #pragma unroll
    for (int it = 0; it < 6; ++it) {
        int e4 = tid + it*256;
        if (e4 < PATCH_V4) {
            int r = e4 / ROWV4;
            int t = e4 - r*ROWV4;
            async_load16(gbase + (size_t)r*XROWF + t*4, &patch[e4*4]);
        }
    }
    __syncthreads();

    // ---- Phase B: conv on threads 0..80 (waves 0-1); GAP colsums on wave 2 ----
    if (tid < 81) {
        const int oy = tid / 27;
        const int ox = (tid / 9) % 3;
        const int oc = tid % 9;
        float acc = conv_b[oc];
        #pragma unroll
        for (int ky = 0; ky < 3; ++ky) {
            #pragma unroll
            for (int kx = 0; kx < 3; ++kx) {
                const float* pp = &patch[(oy*8+ky)*ROWF + (ox*8+kx)*NCH];
                const float* ww = &cw[(ky*3+kx)*81 + oc];
                #pragma unroll
                for (int ic = 0; ic < 9; ++ic) acc += pp[ic] * ww[ic*9];
            }
        }
        co_s[tid] = acc;
    } else if (tid >= 128 && tid < 128+ROWV4) {
        const int k = tid - 128;
        const float4* pv = reinterpret_cast<const float4*>(patch);
        float4 acc = pv[k];
        #pragma unroll
        for (int r = 1; r < PSZ; ++r) {
            float4 v = pv[r*ROWV4 + k];
            acc.x += v.x; acc.y += v.y; acc.z += v.z; acc.w += v.w;
        }
        reinterpret_cast<float4*>(colsum)[k] = acc;
    }
    __syncthreads();

    // ---- Phase C: wg1 clip scales (threads 0..8); GAP fold (threads 128..136) ----
    if (tid < NCH) {
        float n2 = 0.f;
        #pragma unroll
        for (int s9 = 0; s9 < 9; ++s9) {
            float v = co_s[s9*9 + tid];
            n2 += v*v;
        }
        sc1[tid] = 1.0f / fmaxf(sqrtf(n2), 1.0f);
    } else if (tid >= 128 && tid < 128+NCH) {
        const int c = tid - 128;
        float s = 0.f;
        #pragma unroll
        for (int i = 0; i < PSZ; ++i) s += colsum[c + NCH*i];
        gap_s[c] = s * (1.0f / (float)NPIX);
    }
    __syncthreads();

    // ---- Phase D: dense (needs gap), write wg1 ----
    if (tid < 81) {
        float acc = dense_b[tid];
        #pragma unroll
        for (int c = 0; c < NCH; ++c) acc += gap_s[c] * dense_w[c*81 + tid];
        d_s[tid] = acc;

        out[OUT1_OFF + (size_t)j*81 + tid] = co_s[tid] * sc1[tid % 9];
    }
    __syncthreads();

    // ---- Phase E: wg2 clip scales (norm over rows a, per column b) ----
    if (tid < NCH) {
        float n2 = 0.f;
        #pragma unroll
        for (int a = 0; a < 9; ++a) {
            float v = d_s[a*9 + tid];
            n2 += v*v;
        }
        sc2[tid] = 1.0f / fmaxf(sqrtf(n2), 1.0f);
    }
    __syncthreads();

    // ---- Phase F: write wg2 ----
    if (tid < 81) {
        out[OUT2_OFF + (size_t)j*81 + tid] = d_s[tid] * sc2[tid % 9];
    }
}

extern "C" void kernel_launch(void* const* d_in, const int* in_sizes, int n_in,
                              void* d_out, int out_size, void* d_ws, size_t ws_size,
                              hipStream_t stream) {
    const float* x       = (const float*)d_in[0];
    const float* conv_w  = (const float*)d_in[1];
    const float* conv_b  = (const float*)d_in[2];
    const float* dense_w = (const float*)d_in[3];
    const float* dense_b = (const float*)d_in[4];
    float* out = (float*)d_out;

    kgl_kernel<<<8192, 256, 0, stream>>>(x, conv_w, conv_b, dense_w, dense_b, out);
}